// Round 7
// baseline (916.865 us; speedup 1.0000x reference)
//
#include <hip/hip_runtime.h>

#define T_     24
#define LAMDA_ 0.2f

// output layout (flat f32): outs[24,64,256] | cs[64,256] | las[24,64,32] | gas[24,64,256]
#define OFF_CS  393216
#define OFF_LAS 409600
#define OFF_GAS 458752

__device__ __forceinline__ float clamp15(float x){ return fminf(15.f, fmaxf(-15.f, x)); }
__device__ __forceinline__ float rcp_(float x){ return __builtin_amdgcn_rcpf(x); }

// ---------------------------------------------------------------------------
// One block per batch element (64 blocks x 1024 threads). FP32 in, FP32 out.
// R7: __launch_bounds__(1024,4) -> 128-VGPR budget (64 blocks on 256 CUs =
// 1 block/CU is all the occupancy that exists; R6's 64-VGPR cap caused
// scratch spills whose reloads missed L2 -> 580 MB phantom HBM fetch).
// Phase A rows contiguous per slot so each Wih line is fetched once.
// ---------------------------------------------------------------------------
__global__ __launch_bounds__(1024, 4) void spat_kernel(
    const float* __restrict__ li,  const float* __restrict__ gi,
    const float* __restrict__ ls,  const float* __restrict__ gs,
    const float* __restrict__ dist,
    const float* __restrict__ la0, const float* __restrict__ ga0,
    const float* __restrict__ Wcl, const float* __restrict__ bcl,
    const float* __restrict__ Wll, const float* __restrict__ bll, const float* __restrict__ vl,
    const float* __restrict__ Wcg, const float* __restrict__ bcg,
    const float* __restrict__ Wlg, const float* __restrict__ blg, const float* __restrict__ vg,
    const float* __restrict__ Wih, const float* __restrict__ bih, const float* __restrict__ bhh,
    float* __restrict__ out)
{
    __shared__ float Eg[6144];               // exp(2*hf_g[o][s]), o<24, s<256
    __shared__ float El[800];                // exp(2*hf_l), idx l*25+o
    __shared__ __align__(16) union {
        float wcg[6144];                     // Wcg staging (init only)
        struct {
            float sgred[1024];
            float red[800];                  // idx l*25+o
            float gbuf[768];
            float xv[288];
            float cq[256];
        } p;
    } U;
    __shared__ float dstf[256];
    __shared__ float bsum[768];              // bih+bhh for used gate rows
    __shared__ float bcf[48];                // bll|blg
    __shared__ __align__(8) float2 fvl[24], fvg[24];   // (F_d, v_d) packed
    __shared__ float vlf[24], vgf[24], cbuf[2];

    const int b = blockIdx.x, tid = threadIdx.x;
    const int s = tid & 255, ogrp = tid >> 8;

    // ---- small init (before first barrier) ----
    if (tid < 256) dstf[tid] = dist[b*256 + tid];
    if (tid < 24)  { vlf[tid] = vl[tid]; vgf[tid] = vg[tid]; }
    if (tid < 48)  bcf[tid] = (tid < 24) ? bll[tid] : blg[tid - 24];
    if (tid < 768) {
        const int wrow = tid + ((tid >= 256) ? 256 : 0);
        bsum[tid] = bih[wrow] + bhh[wrow];
    }
    if (tid == 0)  { float s1 = 0.f; for (int d = 0; d < 24; d++) s1 += vl[d]; cbuf[0] = s1; }
    if (tid == 1)  { float s1 = 0.f; for (int d = 0; d < 24; d++) s1 += vg[d]; cbuf[1] = s1; }

    // ---- hf_g: thread (s, ogrp) accumulates 6 o's over c<24, j<32 ----
    float acc[6];
#pragma unroll
    for (int i = 0; i < 6; i++) acc[i] = bcg[ogrp*6 + i];

    for (int hc = 0; hc < 3; hc++) {
        for (int k = tid; k < 6144; k += 1024) {
            const int o = k >> 8, r = k & 255;
            U.wcg[k] = Wcg[o*768 + hc*256 + r];
        }
        __syncthreads();
        for (int cc = 0; cc < 8; cc++) {
            const int c = hc*8 + cc;
            const float4* gp = (const float4*)(gs + ((size_t)b*196608 + c*8192 + s*32));
            float gv[32];
#pragma unroll
            for (int m = 0; m < 8; m++) {
                const float4 g = gp[m];
                gv[4*m] = g.x; gv[4*m+1] = g.y; gv[4*m+2] = g.z; gv[4*m+3] = g.w;
            }
#pragma unroll
            for (int i = 0; i < 6; i++) {
                const float4* wp = (const float4*)(U.wcg + ((ogrp*6 + i)*256 + cc*32));
                float a = acc[i];
#pragma unroll
                for (int m = 0; m < 8; m++) {
                    const float4 w = wp[m];
                    a = fmaf(w.x, gv[4*m],   a);
                    a = fmaf(w.y, gv[4*m+1], a);
                    a = fmaf(w.z, gv[4*m+2], a);
                    a = fmaf(w.w, gv[4*m+3], a);
                }
                acc[i] = a;
            }
        }
        __syncthreads();
    }
#pragma unroll
    for (int i = 0; i < 6; i++) Eg[(ogrp*6 + i)*256 + s] = __expf(2.f*clamp15(acc[i]));

    // ---- hf_l -> El (transposed: l*25+o) ----
    if (tid < 768) {
        const int o = tid >> 5, l = tid & 31;
        float a = bcl[o];
        for (int c = 0; c < 24; c++)
            a = fmaf(Wcl[o*24 + c], ls[b*768 + c*32 + l], a);
        El[l*25 + o] = __expf(2.f*clamp15(a));
    }

    // ---- x for t=0 (wcg union dead after hc-loop barrier) ----
    if (tid < 288) {
        if (tid < 32) U.p.xv[tid] = la0[b*32 + tid] * li[b*32 + tid];
        else { const int ss = tid - 32; U.p.xv[tid] = ga0[b*256 + ss] * gi[b*256 + ss]; }
    }
    __syncthreads();

    const int u8 = tid & 7, slot = tid >> 3;   // phase A/C team layout

    for (int t = 0; t < T_; t++) {
        // prefetch next-step inputs for the fused x-build (wave0: li, wave1: gi)
        float liN = 0.f;
        float giN0 = 0.f, giN1 = 0.f, giN2 = 0.f, giN3 = 0.f;
        if (t < T_ - 1) {
            if (tid < 32) liN = li[(t+1)*2048 + b*32 + tid];
            else if (tid >= 64 && tid < 128) {
                const int lane = tid - 64;
                giN0 = gi[(t+1)*16384 + b*256 + lane];
                giN1 = gi[(t+1)*16384 + b*256 + lane + 64];
                giN2 = gi[(t+1)*16384 + b*256 + lane + 128];
                giN3 = gi[(t+1)*16384 + b*256 + lane + 192];
            }
        }

        // ---- A: gates GEMV, 8 lanes/row, 6 contiguous rows per slot ----
        {
            const float4* xp = (const float4*)U.p.xv;
            float4 xq[9];
#pragma unroll
            for (int j = 0; j < 9; j++) xq[j] = xp[j*8 + u8];
            float ar[6];
#pragma unroll
            for (int k = 0; k < 6; k++) {
                const int row  = slot*6 + k;             // contiguous 48 rows/wave
                const int wrow = row + ((row >= 256) ? 256 : 0);
                const float4* wp = (const float4*)(Wih + wrow*288);
                float a0 = 0.f, a1 = 0.f, a2 = 0.f;
#pragma unroll
                for (int j = 0; j < 9; j += 3) {
                    const float4 w0 = wp[j*8 + u8];
                    const float4 w1 = wp[(j+1)*8 + u8];
                    const float4 w2 = wp[(j+2)*8 + u8];
                    a0 = fmaf(w0.x,xq[j].x,a0);   a0 = fmaf(w0.y,xq[j].y,a0);
                    a0 = fmaf(w0.z,xq[j].z,a0);   a0 = fmaf(w0.w,xq[j].w,a0);
                    a1 = fmaf(w1.x,xq[j+1].x,a1); a1 = fmaf(w1.y,xq[j+1].y,a1);
                    a1 = fmaf(w1.z,xq[j+1].z,a1); a1 = fmaf(w1.w,xq[j+1].w,a1);
                    a2 = fmaf(w2.x,xq[j+2].x,a2); a2 = fmaf(w2.y,xq[j+2].y,a2);
                    a2 = fmaf(w2.z,xq[j+2].z,a2); a2 = fmaf(w2.w,xq[j+2].w,a2);
                }
                ar[k] = (a0 + a1) + a2;
            }
#pragma unroll
            for (int k = 0; k < 6; k++) {
                float a = ar[k];
                a += __shfl_xor(a, 1); a += __shfl_xor(a, 2); a += __shfl_xor(a, 4);
                if (u8 == 0) {
                    const int row = slot*6 + k;
                    U.p.gbuf[row] = a + bsum[row];
                }
            }
        }
        __syncthreads();

        // ---- B: c = sig(i)*tanh(g); h = sig(o)*tanh(c) ----
        if (tid < 256) {
            const float ig = U.p.gbuf[tid], gg = U.p.gbuf[256 + tid], ot = U.p.gbuf[512 + tid];
            const float sig_i = rcp_(1.f + __expf(-ig));
            const float th_g  = 1.f - 2.f*rcp_(1.f + __expf(2.f*clamp15(gg)));
            const float c     = sig_i * th_g;
            const float sig_o = rcp_(1.f + __expf(-ot));
            const float th_c  = 1.f - 2.f*rcp_(1.f + __expf(2.f*c));
            const float h     = sig_o * th_c;
            U.p.cq[tid] = c;
            out[t*16384 + b*256 + tid] = h;
            if (t == T_ - 1) out[OFF_CS + b*256 + tid] = c;
        }
        __syncthreads();

        // ---- C: 48 dots x 8-lane teams, conflict-free; F = exp(2y) ----
        if (tid < 384) {
            const int dot = slot;            // tid>>3 < 48
            const float* Wr = (dot < 24) ? (Wll + dot*256) : (Wlg + (dot - 24)*256);
            const float4* wp = (const float4*)Wr;
            const float4* cp = (const float4*)U.p.cq;
            float a0 = 0.f, a1 = 0.f;
#pragma unroll
            for (int j = 0; j < 8; j += 2) {
                const float4 w0 = wp[j*8 + u8],     c0 = cp[j*8 + u8];
                const float4 w1 = wp[(j+1)*8 + u8], c1 = cp[(j+1)*8 + u8];
                a0 = fmaf(w0.x,c0.x,a0); a0 = fmaf(w0.y,c0.y,a0);
                a0 = fmaf(w0.z,c0.z,a0); a0 = fmaf(w0.w,c0.w,a0);
                a1 = fmaf(w1.x,c1.x,a1); a1 = fmaf(w1.y,c1.y,a1);
                a1 = fmaf(w1.z,c1.z,a1); a1 = fmaf(w1.w,c1.w,a1);
            }
            float a = a0 + a1;
            a += __shfl_xor(a, 1); a += __shfl_xor(a, 2); a += __shfl_xor(a, 4);
            if (u8 == 0) {
                const float F = __expf(2.f*clamp15(a + bcf[dot]));
                if (dot < 24) fvl[dot] = make_float2(F, vlf[dot]);
                else          fvg[dot - 24] = make_float2(F, vgf[dot - 24]);
            }
        }
        __syncthreads();

        // ---- D: s_g partials (all) + s_l partials (tid<768); Eg in regs ----
        {
            float Ew[6];
#pragma unroll
            for (int i = 0; i < 6; i++) Ew[i] = Eg[(ogrp*6 + i)*256 + s];
            float a0 = 0.f;
#pragma unroll
            for (int d = 0; d < 24; d++) {
                const float2 p = fvg[d];
                const float r0 = rcp_(fmaf(Ew[0], p.x, 1.f));
                const float r1 = rcp_(fmaf(Ew[1], p.x, 1.f));
                const float r2 = rcp_(fmaf(Ew[2], p.x, 1.f));
                const float r3 = rcp_(fmaf(Ew[3], p.x, 1.f));
                const float r4 = rcp_(fmaf(Ew[4], p.x, 1.f));
                const float r5 = rcp_(fmaf(Ew[5], p.x, 1.f));
                a0 = fmaf(p.y, ((r0 + r1) + (r2 + r3)) + (r4 + r5), a0);
            }
            U.p.sgred[tid] = a0;
        }
        if (tid < 768) {
            const int l = tid / 24, o = tid - l*24;
            const float E = El[l*25 + o];
            float b0 = 0.f, b1 = 0.f;
#pragma unroll
            for (int d = 0; d < 24; d += 2) {
                const float2 p0 = fvl[d], p1 = fvl[d+1];
                b0 = fmaf(p0.y, rcp_(fmaf(E, p0.x, 1.f)), b0);
                b1 = fmaf(p1.y, rcp_(fmaf(E, p1.x, 1.f)), b1);
            }
            U.p.red[l*25 + o] = b0 + b1;
        }
        __syncthreads();

        // ---- E: both softmaxes + next-step x-build ----
        if (tid < 32) {                       // wave0: s_l softmax
            float tot = 0.f;
#pragma unroll
            for (int o2 = 0; o2 < 24; o2++) tot += U.p.red[tid*25 + o2];
            const float sv = 24.f*cbuf[0] - 2.f*tot;
            float m = sv;
#pragma unroll
            for (int mk = 16; mk >= 1; mk >>= 1) m = fmaxf(m, __shfl_xor(m, mk));
            const float e = __expf(sv - m);
            float ss = e;
#pragma unroll
            for (int mk = 16; mk >= 1; mk >>= 1) ss += __shfl_xor(ss, mk);
            const float r = e * rcp_(ss);
            out[OFF_LAS + t*2048 + b*32 + tid] = r;
            if (t < T_ - 1) U.p.xv[tid] = r * liN;
        } else if (tid >= 64 && tid < 128) {  // wave1: s_g softmax, 4 s/lane
            const int lane = tid - 64;
            float vv0, vv1, vv2, vv3;
            {
                const float t0 = U.p.sgred[lane]     + U.p.sgred[256+lane]     + U.p.sgred[512+lane]     + U.p.sgred[768+lane];
                const float t1 = U.p.sgred[lane+64]  + U.p.sgred[256+lane+64]  + U.p.sgred[512+lane+64]  + U.p.sgred[768+lane+64];
                const float t2 = U.p.sgred[lane+128] + U.p.sgred[256+lane+128] + U.p.sgred[512+lane+128] + U.p.sgred[768+lane+128];
                const float t3 = U.p.sgred[lane+192] + U.p.sgred[256+lane+192] + U.p.sgred[512+lane+192] + U.p.sgred[768+lane+192];
                vv0 = (1.f-LAMDA_)*(24.f*cbuf[1] - 2.f*t0) + LAMDA_*dstf[lane];
                vv1 = (1.f-LAMDA_)*(24.f*cbuf[1] - 2.f*t1) + LAMDA_*dstf[lane+64];
                vv2 = (1.f-LAMDA_)*(24.f*cbuf[1] - 2.f*t2) + LAMDA_*dstf[lane+128];
                vv3 = (1.f-LAMDA_)*(24.f*cbuf[1] - 2.f*t3) + LAMDA_*dstf[lane+192];
            }
            float m = fmaxf(fmaxf(vv0, vv1), fmaxf(vv2, vv3));
#pragma unroll
            for (int mk = 32; mk >= 1; mk >>= 1) m = fmaxf(m, __shfl_xor(m, mk));
            const float e0 = __expf(vv0 - m), e1 = __expf(vv1 - m);
            const float e2 = __expf(vv2 - m), e3 = __expf(vv3 - m);
            float ss = (e0 + e1) + (e2 + e3);
#pragma unroll
            for (int mk = 32; mk >= 1; mk >>= 1) ss += __shfl_xor(ss, mk);
            const float inv = rcp_(ss);
            const float r0 = e0*inv, r1 = e1*inv, r2 = e2*inv, r3 = e3*inv;
            float* og = out + OFF_GAS + t*16384 + b*256;
            og[lane] = r0; og[lane+64] = r1; og[lane+128] = r2; og[lane+192] = r3;
            if (t < T_ - 1) {
                U.p.xv[32+lane]     = r0 * giN0;
                U.p.xv[32+lane+64]  = r1 * giN1;
                U.p.xv[32+lane+128] = r2 * giN2;
                U.p.xv[32+lane+192] = r3 * giN3;
            }
        }
        __syncthreads();
    }
}

extern "C" void kernel_launch(void* const* d_in, const int* in_sizes, int n_in,
                              void* d_out, int out_size, void* d_ws, size_t ws_size,
                              hipStream_t stream)
{
    const float* li   = (const float*)d_in[0];
    const float* gi   = (const float*)d_in[1];
    const float* ls   = (const float*)d_in[2];
    const float* gs   = (const float*)d_in[3];
    const float* dist = (const float*)d_in[4];
    const float* la0  = (const float*)d_in[5];
    const float* ga0  = (const float*)d_in[6];
    const float* Wcl  = (const float*)d_in[7];
    const float* bcl  = (const float*)d_in[8];
    const float* Wll  = (const float*)d_in[9];
    const float* bll  = (const float*)d_in[10];
    const float* vl   = (const float*)d_in[11];
    const float* Wcg  = (const float*)d_in[12];
    const float* bcg  = (const float*)d_in[13];
    const float* Wlg  = (const float*)d_in[14];
    const float* blg  = (const float*)d_in[15];
    const float* vg   = (const float*)d_in[16];
    const float* Wih  = (const float*)d_in[17];
    const float* bih  = (const float*)d_in[18];
    const float* bhh  = (const float*)d_in[19];

    spat_kernel<<<64, 1024, 0, stream>>>(li, gi, ls, gs, dist, la0, ga0,
                                         Wcl, bcl, Wll, bll, vl,
                                         Wcg, bcg, Wlg, blg, vg,
                                         Wih, bih, bhh, (float*)d_out);
}

// Round 8
// 912.675 us; speedup vs baseline: 1.0046x; 1.0046x over previous
//
#include <hip/hip_runtime.h>

#define T_     24
#define LAMDA_ 0.2f

// output layout (flat f32): outs[24,64,256] | cs[64,256] | las[24,64,32] | gas[24,64,256]
#define OFF_CS  393216
#define OFF_LAS 409600
#define OFF_GAS 458752

__device__ __forceinline__ float clamp15(float x){ return fminf(15.f, fmaxf(-15.f, x)); }
__device__ __forceinline__ float rcp_(float x){ return __builtin_amdgcn_rcpf(x); }

// ---------------------------------------------------------------------------
// One block per batch element (64 blocks x 1024 threads). FP32 in, FP32 out.
// R8: __launch_bounds__(1024, 1) -> 1 block/CU target -> 128-VGPR cap.
// R6/R7's 64-VGPR cap (2-blocks/CU target) forced ~9 dwords/thread/step of
// scratch spills whose reloads (~9x amplification) hit HBM: WRITE 59 MB /
// FETCH 575 MB phantom traffic = the whole 823 us. We launch 64 blocks on
// 256 CUs, so 1 block/CU costs nothing.
// ---------------------------------------------------------------------------
__global__ __launch_bounds__(1024, 1) void spat_kernel(
    const float* __restrict__ li,  const float* __restrict__ gi,
    const float* __restrict__ ls,  const float* __restrict__ gs,
    const float* __restrict__ dist,
    const float* __restrict__ la0, const float* __restrict__ ga0,
    const float* __restrict__ Wcl, const float* __restrict__ bcl,
    const float* __restrict__ Wll, const float* __restrict__ bll, const float* __restrict__ vl,
    const float* __restrict__ Wcg, const float* __restrict__ bcg,
    const float* __restrict__ Wlg, const float* __restrict__ blg, const float* __restrict__ vg,
    const float* __restrict__ Wih, const float* __restrict__ bih, const float* __restrict__ bhh,
    float* __restrict__ out)
{
    __shared__ float Eg[6144];               // exp(2*hf_g[o][s]), o<24, s<256
    __shared__ float El[800];                // exp(2*hf_l), idx l*25+o
    __shared__ __align__(16) union {
        float wcg[6144];                     // Wcg staging (init only)
        struct {
            float sgred[1024];
            float red[800];                  // idx l*25+o
            float gbuf[768];
            float xv[288];
            float cq[256];
        } p;
    } U;
    __shared__ float dstf[256];
    __shared__ float bsum[768];              // bih+bhh for used gate rows
    __shared__ float bcf[48];                // bll|blg
    __shared__ __align__(8) float2 fvl[24], fvg[24];   // (F_d, v_d) packed
    __shared__ float vlf[24], vgf[24], cbuf[2];

    const int b = blockIdx.x, tid = threadIdx.x;
    const int s = tid & 255, ogrp = tid >> 8;

    // ---- small init (before first barrier) ----
    if (tid < 256) dstf[tid] = dist[b*256 + tid];
    if (tid < 24)  { vlf[tid] = vl[tid]; vgf[tid] = vg[tid]; }
    if (tid < 48)  bcf[tid] = (tid < 24) ? bll[tid] : blg[tid - 24];
    if (tid < 768) {
        const int wrow = tid + ((tid >= 256) ? 256 : 0);
        bsum[tid] = bih[wrow] + bhh[wrow];
    }
    if (tid == 0)  { float s1 = 0.f; for (int d = 0; d < 24; d++) s1 += vl[d]; cbuf[0] = s1; }
    if (tid == 1)  { float s1 = 0.f; for (int d = 0; d < 24; d++) s1 += vg[d]; cbuf[1] = s1; }

    // ---- hf_g: thread (s, ogrp) accumulates 6 o's over c<24, j<32 ----
    float acc[6];
#pragma unroll
    for (int i = 0; i < 6; i++) acc[i] = bcg[ogrp*6 + i];

    for (int hc = 0; hc < 3; hc++) {
        for (int k = tid; k < 6144; k += 1024) {
            const int o = k >> 8, r = k & 255;
            U.wcg[k] = Wcg[o*768 + hc*256 + r];
        }
        __syncthreads();
        for (int cc = 0; cc < 8; cc++) {
            const int c = hc*8 + cc;
            const float4* gp = (const float4*)(gs + ((size_t)b*196608 + c*8192 + s*32));
            float gv[32];
#pragma unroll
            for (int m = 0; m < 8; m++) {
                const float4 g = gp[m];
                gv[4*m] = g.x; gv[4*m+1] = g.y; gv[4*m+2] = g.z; gv[4*m+3] = g.w;
            }
#pragma unroll
            for (int i = 0; i < 6; i++) {
                const float4* wp = (const float4*)(U.wcg + ((ogrp*6 + i)*256 + cc*32));
                float a = acc[i];
#pragma unroll
                for (int m = 0; m < 8; m++) {
                    const float4 w = wp[m];
                    a = fmaf(w.x, gv[4*m],   a);
                    a = fmaf(w.y, gv[4*m+1], a);
                    a = fmaf(w.z, gv[4*m+2], a);
                    a = fmaf(w.w, gv[4*m+3], a);
                }
                acc[i] = a;
            }
        }
        __syncthreads();
    }
#pragma unroll
    for (int i = 0; i < 6; i++) Eg[(ogrp*6 + i)*256 + s] = __expf(2.f*clamp15(acc[i]));

    // ---- hf_l -> El (transposed: l*25+o) ----
    if (tid < 768) {
        const int o = tid >> 5, l = tid & 31;
        float a = bcl[o];
        for (int c = 0; c < 24; c++)
            a = fmaf(Wcl[o*24 + c], ls[b*768 + c*32 + l], a);
        El[l*25 + o] = __expf(2.f*clamp15(a));
    }

    // ---- x for t=0 (wcg union dead after hc-loop barrier) ----
    if (tid < 288) {
        if (tid < 32) U.p.xv[tid] = la0[b*32 + tid] * li[b*32 + tid];
        else { const int ss = tid - 32; U.p.xv[tid] = ga0[b*256 + ss] * gi[b*256 + ss]; }
    }
    __syncthreads();

    const int u8 = tid & 7, slot = tid >> 3;   // phase A/C team layout

    for (int t = 0; t < T_; t++) {
        // prefetch next-step inputs for the fused x-build (wave0: li, wave1: gi)
        float liN = 0.f;
        float giN0 = 0.f, giN1 = 0.f, giN2 = 0.f, giN3 = 0.f;
        if (t < T_ - 1) {
            if (tid < 32) liN = li[(t+1)*2048 + b*32 + tid];
            else if (tid >= 64 && tid < 128) {
                const int lane = tid - 64;
                giN0 = gi[(t+1)*16384 + b*256 + lane];
                giN1 = gi[(t+1)*16384 + b*256 + lane + 64];
                giN2 = gi[(t+1)*16384 + b*256 + lane + 128];
                giN3 = gi[(t+1)*16384 + b*256 + lane + 192];
            }
        }

        // ---- A: gates GEMV, 8 lanes/row, 6 contiguous rows per slot ----
        {
            const float4* xp = (const float4*)U.p.xv;
            float4 xq[9];
#pragma unroll
            for (int j = 0; j < 9; j++) xq[j] = xp[j*8 + u8];
            float ar[6];
#pragma unroll
            for (int k = 0; k < 6; k++) {
                const int row  = slot*6 + k;             // contiguous 48 rows/wave
                const int wrow = row + ((row >= 256) ? 256 : 0);
                const float4* wp = (const float4*)(Wih + wrow*288);
                float a0 = 0.f, a1 = 0.f, a2 = 0.f;
#pragma unroll
                for (int j = 0; j < 9; j += 3) {
                    const float4 w0 = wp[j*8 + u8];
                    const float4 w1 = wp[(j+1)*8 + u8];
                    const float4 w2 = wp[(j+2)*8 + u8];
                    a0 = fmaf(w0.x,xq[j].x,a0);   a0 = fmaf(w0.y,xq[j].y,a0);
                    a0 = fmaf(w0.z,xq[j].z,a0);   a0 = fmaf(w0.w,xq[j].w,a0);
                    a1 = fmaf(w1.x,xq[j+1].x,a1); a1 = fmaf(w1.y,xq[j+1].y,a1);
                    a1 = fmaf(w1.z,xq[j+1].z,a1); a1 = fmaf(w1.w,xq[j+1].w,a1);
                    a2 = fmaf(w2.x,xq[j+2].x,a2); a2 = fmaf(w2.y,xq[j+2].y,a2);
                    a2 = fmaf(w2.z,xq[j+2].z,a2); a2 = fmaf(w2.w,xq[j+2].w,a2);
                }
                ar[k] = (a0 + a1) + a2;
            }
#pragma unroll
            for (int k = 0; k < 6; k++) {
                float a = ar[k];
                a += __shfl_xor(a, 1); a += __shfl_xor(a, 2); a += __shfl_xor(a, 4);
                if (u8 == 0) {
                    const int row = slot*6 + k;
                    U.p.gbuf[row] = a + bsum[row];
                }
            }
        }
        __syncthreads();

        // ---- B: c = sig(i)*tanh(g); h = sig(o)*tanh(c) ----
        if (tid < 256) {
            const float ig = U.p.gbuf[tid], gg = U.p.gbuf[256 + tid], ot = U.p.gbuf[512 + tid];
            const float sig_i = rcp_(1.f + __expf(-ig));
            const float th_g  = 1.f - 2.f*rcp_(1.f + __expf(2.f*clamp15(gg)));
            const float c     = sig_i * th_g;
            const float sig_o = rcp_(1.f + __expf(-ot));
            const float th_c  = 1.f - 2.f*rcp_(1.f + __expf(2.f*c));
            const float h     = sig_o * th_c;
            U.p.cq[tid] = c;
            out[t*16384 + b*256 + tid] = h;
            if (t == T_ - 1) out[OFF_CS + b*256 + tid] = c;
        }
        __syncthreads();

        // ---- C: 48 dots x 8-lane teams, conflict-free; F = exp(2y) ----
        if (tid < 384) {
            const int dot = slot;            // tid>>3 < 48
            const float* Wr = (dot < 24) ? (Wll + dot*256) : (Wlg + (dot - 24)*256);
            const float4* wp = (const float4*)Wr;
            const float4* cp = (const float4*)U.p.cq;
            float a0 = 0.f, a1 = 0.f;
#pragma unroll
            for (int j = 0; j < 8; j += 2) {
                const float4 w0 = wp[j*8 + u8],     c0 = cp[j*8 + u8];
                const float4 w1 = wp[(j+1)*8 + u8], c1 = cp[(j+1)*8 + u8];
                a0 = fmaf(w0.x,c0.x,a0); a0 = fmaf(w0.y,c0.y,a0);
                a0 = fmaf(w0.z,c0.z,a0); a0 = fmaf(w0.w,c0.w,a0);
                a1 = fmaf(w1.x,c1.x,a1); a1 = fmaf(w1.y,c1.y,a1);
                a1 = fmaf(w1.z,c1.z,a1); a1 = fmaf(w1.w,c1.w,a1);
            }
            float a = a0 + a1;
            a += __shfl_xor(a, 1); a += __shfl_xor(a, 2); a += __shfl_xor(a, 4);
            if (u8 == 0) {
                const float F = __expf(2.f*clamp15(a + bcf[dot]));
                if (dot < 24) fvl[dot] = make_float2(F, vlf[dot]);
                else          fvg[dot - 24] = make_float2(F, vgf[dot - 24]);
            }
        }
        __syncthreads();

        // ---- D: s_g partials (all) + s_l partials (tid<768); Eg in regs ----
        {
            float Ew[6];
#pragma unroll
            for (int i = 0; i < 6; i++) Ew[i] = Eg[(ogrp*6 + i)*256 + s];
            float a0 = 0.f;
#pragma unroll
            for (int d = 0; d < 24; d++) {
                const float2 p = fvg[d];
                const float r0 = rcp_(fmaf(Ew[0], p.x, 1.f));
                const float r1 = rcp_(fmaf(Ew[1], p.x, 1.f));
                const float r2 = rcp_(fmaf(Ew[2], p.x, 1.f));
                const float r3 = rcp_(fmaf(Ew[3], p.x, 1.f));
                const float r4 = rcp_(fmaf(Ew[4], p.x, 1.f));
                const float r5 = rcp_(fmaf(Ew[5], p.x, 1.f));
                a0 = fmaf(p.y, ((r0 + r1) + (r2 + r3)) + (r4 + r5), a0);
            }
            U.p.sgred[tid] = a0;
        }
        if (tid < 768) {
            const int l = tid / 24, o = tid - l*24;
            const float E = El[l*25 + o];
            float b0 = 0.f, b1 = 0.f;
#pragma unroll
            for (int d = 0; d < 24; d += 2) {
                const float2 p0 = fvl[d], p1 = fvl[d+1];
                b0 = fmaf(p0.y, rcp_(fmaf(E, p0.x, 1.f)), b0);
                b1 = fmaf(p1.y, rcp_(fmaf(E, p1.x, 1.f)), b1);
            }
            U.p.red[l*25 + o] = b0 + b1;
        }
        __syncthreads();

        // ---- E: both softmaxes + next-step x-build ----
        if (tid < 32) {                       // wave0: s_l softmax
            float tot = 0.f;
#pragma unroll
            for (int o2 = 0; o2 < 24; o2++) tot += U.p.red[tid*25 + o2];
            const float sv = 24.f*cbuf[0] - 2.f*tot;
            float m = sv;
#pragma unroll
            for (int mk = 16; mk >= 1; mk >>= 1) m = fmaxf(m, __shfl_xor(m, mk));
            const float e = __expf(sv - m);
            float ss = e;
#pragma unroll
            for (int mk = 16; mk >= 1; mk >>= 1) ss += __shfl_xor(ss, mk);
            const float r = e * rcp_(ss);
            out[OFF_LAS + t*2048 + b*32 + tid] = r;
            if (t < T_ - 1) U.p.xv[tid] = r * liN;
        } else if (tid >= 64 && tid < 128) {  // wave1: s_g softmax, 4 s/lane
            const int lane = tid - 64;
            float vv0, vv1, vv2, vv3;
            {
                const float t0 = U.p.sgred[lane]     + U.p.sgred[256+lane]     + U.p.sgred[512+lane]     + U.p.sgred[768+lane];
                const float t1 = U.p.sgred[lane+64]  + U.p.sgred[256+lane+64]  + U.p.sgred[512+lane+64]  + U.p.sgred[768+lane+64];
                const float t2 = U.p.sgred[lane+128] + U.p.sgred[256+lane+128] + U.p.sgred[512+lane+128] + U.p.sgred[768+lane+128];
                const float t3 = U.p.sgred[lane+192] + U.p.sgred[256+lane+192] + U.p.sgred[512+lane+192] + U.p.sgred[768+lane+192];
                vv0 = (1.f-LAMDA_)*(24.f*cbuf[1] - 2.f*t0) + LAMDA_*dstf[lane];
                vv1 = (1.f-LAMDA_)*(24.f*cbuf[1] - 2.f*t1) + LAMDA_*dstf[lane+64];
                vv2 = (1.f-LAMDA_)*(24.f*cbuf[1] - 2.f*t2) + LAMDA_*dstf[lane+128];
                vv3 = (1.f-LAMDA_)*(24.f*cbuf[1] - 2.f*t3) + LAMDA_*dstf[lane+192];
            }
            float m = fmaxf(fmaxf(vv0, vv1), fmaxf(vv2, vv3));
#pragma unroll
            for (int mk = 32; mk >= 1; mk >>= 1) m = fmaxf(m, __shfl_xor(m, mk));
            const float e0 = __expf(vv0 - m), e1 = __expf(vv1 - m);
            const float e2 = __expf(vv2 - m), e3 = __expf(vv3 - m);
            float ss = (e0 + e1) + (e2 + e3);
#pragma unroll
            for (int mk = 32; mk >= 1; mk >>= 1) ss += __shfl_xor(ss, mk);
            const float inv = rcp_(ss);
            const float r0 = e0*inv, r1 = e1*inv, r2 = e2*inv, r3 = e3*inv;
            float* og = out + OFF_GAS + t*16384 + b*256;
            og[lane] = r0; og[lane+64] = r1; og[lane+128] = r2; og[lane+192] = r3;
            if (t < T_ - 1) {
                U.p.xv[32+lane]     = r0 * giN0;
                U.p.xv[32+lane+64]  = r1 * giN1;
                U.p.xv[32+lane+128] = r2 * giN2;
                U.p.xv[32+lane+192] = r3 * giN3;
            }
        }
        __syncthreads();
    }
}

extern "C" void kernel_launch(void* const* d_in, const int* in_sizes, int n_in,
                              void* d_out, int out_size, void* d_ws, size_t ws_size,
                              hipStream_t stream)
{
    const float* li   = (const float*)d_in[0];
    const float* gi   = (const float*)d_in[1];
    const float* ls   = (const float*)d_in[2];
    const float* gs   = (const float*)d_in[3];
    const float* dist = (const float*)d_in[4];
    const float* la0  = (const float*)d_in[5];
    const float* ga0  = (const float*)d_in[6];
    const float* Wcl  = (const float*)d_in[7];
    const float* bcl  = (const float*)d_in[8];
    const float* Wll  = (const float*)d_in[9];
    const float* bll  = (const float*)d_in[10];
    const float* vl   = (const float*)d_in[11];
    const float* Wcg  = (const float*)d_in[12];
    const float* bcg  = (const float*)d_in[13];
    const float* Wlg  = (const float*)d_in[14];
    const float* blg  = (const float*)d_in[15];
    const float* vg   = (const float*)d_in[16];
    const float* Wih  = (const float*)d_in[17];
    const float* bih  = (const float*)d_in[18];
    const float* bhh  = (const float*)d_in[19];

    spat_kernel<<<64, 1024, 0, stream>>>(li, gi, ls, gs, dist, la0, ga0,
                                         Wcl, bcl, Wll, bll, vl,
                                         Wcg, bcg, Wlg, blg, vg,
                                         Wih, bih, bhh, (float*)d_out);
}

// Round 9
// 902.160 us; speedup vs baseline: 1.0163x; 1.0117x over previous
//
#include <hip/hip_runtime.h>

#define T_     24
#define LAMDA_ 0.2f

// output layout (flat f32): outs[24,64,256] | cs[64,256] | las[24,64,32] | gas[24,64,256]
#define OFF_CS  393216
#define OFF_LAS 409600
#define OFF_GAS 458752

__device__ __forceinline__ float clamp15(float x){ return fminf(15.f, fmaxf(-15.f, x)); }
__device__ __forceinline__ float rcp_(float x){ return __builtin_amdgcn_rcpf(x); }

// ---------------------------------------------------------------------------
// One block per batch element (64 blocks x 1024 threads). FP32 in, FP32 out.
// R9: the 64-VGPR cap is immovable (launch_bounds had no effect R6-R8), so
// phase A is restructured to FIT: x cached in 3-chunk x[3] float4 (12 regs)
// instead of xq[9] (36 regs); ar[6] partials accumulate across chunks.
// Peak live ~50 regs -> zero scratch. (R6-R8: 9-10 spilled dw/thread/step
// -> 56 MB scratch stores + ~6x reload amplification = 575 MB fetch = the
// whole 820 us.) Init conv gv[32] -> 2x gv[16] for the same reason.
// ---------------------------------------------------------------------------
__global__ __launch_bounds__(1024, 1) void spat_kernel(
    const float* __restrict__ li,  const float* __restrict__ gi,
    const float* __restrict__ ls,  const float* __restrict__ gs,
    const float* __restrict__ dist,
    const float* __restrict__ la0, const float* __restrict__ ga0,
    const float* __restrict__ Wcl, const float* __restrict__ bcl,
    const float* __restrict__ Wll, const float* __restrict__ bll, const float* __restrict__ vl,
    const float* __restrict__ Wcg, const float* __restrict__ bcg,
    const float* __restrict__ Wlg, const float* __restrict__ blg, const float* __restrict__ vg,
    const float* __restrict__ Wih, const float* __restrict__ bih, const float* __restrict__ bhh,
    float* __restrict__ out)
{
    __shared__ float Eg[6144];               // exp(2*hf_g[o][s]), o<24, s<256
    __shared__ float El[800];                // exp(2*hf_l), idx l*25+o
    __shared__ __align__(16) union {
        float wcg[6144];                     // Wcg staging (init only)
        struct {
            float sgred[1024];
            float red[800];                  // idx l*25+o
            float gbuf[768];
            float xv[288];
            float cq[256];
        } p;
    } U;
    __shared__ float dstf[256];
    __shared__ float bsum[768];              // bih+bhh for used gate rows
    __shared__ float bcf[48];                // bll|blg
    __shared__ __align__(8) float2 fvl[24], fvg[24];   // (F_d, v_d) packed
    __shared__ float vlf[24], vgf[24], cbuf[2];

    const int b = blockIdx.x, tid = threadIdx.x;
    const int s = tid & 255, ogrp = tid >> 8;

    // ---- small init (before first barrier) ----
    if (tid < 256) dstf[tid] = dist[b*256 + tid];
    if (tid < 24)  { vlf[tid] = vl[tid]; vgf[tid] = vg[tid]; }
    if (tid < 48)  bcf[tid] = (tid < 24) ? bll[tid] : blg[tid - 24];
    if (tid < 768) {
        const int wrow = tid + ((tid >= 256) ? 256 : 0);
        bsum[tid] = bih[wrow] + bhh[wrow];
    }
    if (tid == 0)  { float s1 = 0.f; for (int d = 0; d < 24; d++) s1 += vl[d]; cbuf[0] = s1; }
    if (tid == 1)  { float s1 = 0.f; for (int d = 0; d < 24; d++) s1 += vg[d]; cbuf[1] = s1; }

    // ---- hf_g: thread (s, ogrp) accumulates 6 o's over c<24, j<32 ----
    float acc[6];
#pragma unroll
    for (int i = 0; i < 6; i++) acc[i] = bcg[ogrp*6 + i];

    for (int hc = 0; hc < 3; hc++) {
        for (int k = tid; k < 6144; k += 1024) {
            const int o = k >> 8, r = k & 255;
            U.wcg[k] = Wcg[o*768 + hc*256 + r];
        }
        __syncthreads();
        for (int cc = 0; cc < 8; cc++) {
            const int c = hc*8 + cc;
            const float4* gp = (const float4*)(gs + ((size_t)b*196608 + c*8192 + s*32));
#pragma unroll
            for (int h = 0; h < 2; h++) {            // two 16-float halves of j
                float gv[16];
#pragma unroll
                for (int m = 0; m < 4; m++) {
                    const float4 g = gp[h*4 + m];
                    gv[4*m] = g.x; gv[4*m+1] = g.y; gv[4*m+2] = g.z; gv[4*m+3] = g.w;
                }
#pragma unroll
                for (int i = 0; i < 6; i++) {
                    const float4* wp = (const float4*)(U.wcg + ((ogrp*6 + i)*256 + cc*32)) + h*4;
                    float a = acc[i];
#pragma unroll
                    for (int m = 0; m < 4; m++) {
                        const float4 w = wp[m];
                        a = fmaf(w.x, gv[4*m],   a);
                        a = fmaf(w.y, gv[4*m+1], a);
                        a = fmaf(w.z, gv[4*m+2], a);
                        a = fmaf(w.w, gv[4*m+3], a);
                    }
                    acc[i] = a;
                }
            }
        }
        __syncthreads();
    }
#pragma unroll
    for (int i = 0; i < 6; i++) Eg[(ogrp*6 + i)*256 + s] = __expf(2.f*clamp15(acc[i]));

    // ---- hf_l -> El (transposed: l*25+o) ----
    if (tid < 768) {
        const int o = tid >> 5, l = tid & 31;
        float a = bcl[o];
        for (int c = 0; c < 24; c++)
            a = fmaf(Wcl[o*24 + c], ls[b*768 + c*32 + l], a);
        El[l*25 + o] = __expf(2.f*clamp15(a));
    }

    // ---- x for t=0 (wcg union dead after hc-loop barrier) ----
    if (tid < 288) {
        if (tid < 32) U.p.xv[tid] = la0[b*32 + tid] * li[b*32 + tid];
        else { const int ss = tid - 32; U.p.xv[tid] = ga0[b*256 + ss] * gi[b*256 + ss]; }
    }
    __syncthreads();

    const int u8 = tid & 7, slot = tid >> 3;   // phase A/C team layout
    const int rbase = slot*6;                  // 6 contiguous rows per slot

    for (int t = 0; t < T_; t++) {
        // prefetch next-step inputs for the fused x-build (wave0: li, wave1: gi)
        float liN = 0.f;
        float giN0 = 0.f, giN1 = 0.f, giN2 = 0.f, giN3 = 0.f;
        if (t < T_ - 1) {
            if (tid < 32) liN = li[(t+1)*2048 + b*32 + tid];
            else if (tid >= 64 && tid < 128) {
                const int lane = tid - 64;
                giN0 = gi[(t+1)*16384 + b*256 + lane];
                giN1 = gi[(t+1)*16384 + b*256 + lane + 64];
                giN2 = gi[(t+1)*16384 + b*256 + lane + 128];
                giN3 = gi[(t+1)*16384 + b*256 + lane + 192];
            }
        }

        // ---- A: gates GEMV, 8 lanes/row, 3-chunk x register cache ----
        {
            const float4* xp = (const float4*)U.p.xv;
            float ar[6];
#pragma unroll
            for (int k = 0; k < 6; k++) ar[k] = 0.f;
#pragma unroll
            for (int jc = 0; jc < 3; jc++) {
                const float4 x0 = xp[(jc*3 + 0)*8 + u8];
                const float4 x1 = xp[(jc*3 + 1)*8 + u8];
                const float4 x2 = xp[(jc*3 + 2)*8 + u8];
#pragma unroll
                for (int k = 0; k < 6; k++) {
                    const int row  = rbase + k;
                    const int wrow = row + ((row >= 256) ? 256 : 0);
                    const float4* wp = (const float4*)(Wih + wrow*288) + jc*24 + u8;
                    const float4 w0 = wp[0], w1 = wp[8], w2 = wp[16];
                    float a = ar[k];
                    a = fmaf(w0.x,x0.x,a); a = fmaf(w0.y,x0.y,a);
                    a = fmaf(w0.z,x0.z,a); a = fmaf(w0.w,x0.w,a);
                    a = fmaf(w1.x,x1.x,a); a = fmaf(w1.y,x1.y,a);
                    a = fmaf(w1.z,x1.z,a); a = fmaf(w1.w,x1.w,a);
                    a = fmaf(w2.x,x2.x,a); a = fmaf(w2.y,x2.y,a);
                    a = fmaf(w2.z,x2.z,a); a = fmaf(w2.w,x2.w,a);
                    ar[k] = a;
                }
            }
#pragma unroll
            for (int k = 0; k < 6; k++) {
                float a = ar[k];
                a += __shfl_xor(a, 1); a += __shfl_xor(a, 2); a += __shfl_xor(a, 4);
                if (u8 == 0) {
                    const int row = rbase + k;
                    U.p.gbuf[row] = a + bsum[row];
                }
            }
        }
        __syncthreads();

        // ---- B: c = sig(i)*tanh(g); h = sig(o)*tanh(c) ----
        if (tid < 256) {
            const float ig = U.p.gbuf[tid], gg = U.p.gbuf[256 + tid], ot = U.p.gbuf[512 + tid];
            const float sig_i = rcp_(1.f + __expf(-ig));
            const float th_g  = 1.f - 2.f*rcp_(1.f + __expf(2.f*clamp15(gg)));
            const float c     = sig_i * th_g;
            const float sig_o = rcp_(1.f + __expf(-ot));
            const float th_c  = 1.f - 2.f*rcp_(1.f + __expf(2.f*c));
            const float h     = sig_o * th_c;
            U.p.cq[tid] = c;
            out[t*16384 + b*256 + tid] = h;
            if (t == T_ - 1) out[OFF_CS + b*256 + tid] = c;
        }
        __syncthreads();

        // ---- C: 48 dots x 8-lane teams, conflict-free; F = exp(2y) ----
        if (tid < 384) {
            const int dot = slot;            // tid>>3 < 48
            const float* Wr = (dot < 24) ? (Wll + dot*256) : (Wlg + (dot - 24)*256);
            const float4* wp = (const float4*)Wr;
            const float4* cp = (const float4*)U.p.cq;
            float a0 = 0.f, a1 = 0.f;
#pragma unroll
            for (int j = 0; j < 8; j += 2) {
                const float4 w0 = wp[j*8 + u8],     c0 = cp[j*8 + u8];
                const float4 w1 = wp[(j+1)*8 + u8], c1 = cp[(j+1)*8 + u8];
                a0 = fmaf(w0.x,c0.x,a0); a0 = fmaf(w0.y,c0.y,a0);
                a0 = fmaf(w0.z,c0.z,a0); a0 = fmaf(w0.w,c0.w,a0);
                a1 = fmaf(w1.x,c1.x,a1); a1 = fmaf(w1.y,c1.y,a1);
                a1 = fmaf(w1.z,c1.z,a1); a1 = fmaf(w1.w,c1.w,a1);
            }
            float a = a0 + a1;
            a += __shfl_xor(a, 1); a += __shfl_xor(a, 2); a += __shfl_xor(a, 4);
            if (u8 == 0) {
                const float F = __expf(2.f*clamp15(a + bcf[dot]));
                if (dot < 24) fvl[dot] = make_float2(F, vlf[dot]);
                else          fvg[dot - 24] = make_float2(F, vgf[dot - 24]);
            }
        }
        __syncthreads();

        // ---- D: s_g partials (all) + s_l partials (tid<768); Eg in regs ----
        {
            float Ew[6];
#pragma unroll
            for (int i = 0; i < 6; i++) Ew[i] = Eg[(ogrp*6 + i)*256 + s];
            float a0 = 0.f;
#pragma unroll
            for (int d = 0; d < 24; d++) {
                const float2 p = fvg[d];
                const float r0 = rcp_(fmaf(Ew[0], p.x, 1.f));
                const float r1 = rcp_(fmaf(Ew[1], p.x, 1.f));
                const float r2 = rcp_(fmaf(Ew[2], p.x, 1.f));
                const float r3 = rcp_(fmaf(Ew[3], p.x, 1.f));
                const float r4 = rcp_(fmaf(Ew[4], p.x, 1.f));
                const float r5 = rcp_(fmaf(Ew[5], p.x, 1.f));
                a0 = fmaf(p.y, ((r0 + r1) + (r2 + r3)) + (r4 + r5), a0);
            }
            U.p.sgred[tid] = a0;
        }
        if (tid < 768) {
            const int l = tid / 24, o = tid - l*24;
            const float E = El[l*25 + o];
            float b0 = 0.f, b1 = 0.f;
#pragma unroll
            for (int d = 0; d < 24; d += 2) {
                const float2 p0 = fvl[d], p1 = fvl[d+1];
                b0 = fmaf(p0.y, rcp_(fmaf(E, p0.x, 1.f)), b0);
                b1 = fmaf(p1.y, rcp_(fmaf(E, p1.x, 1.f)), b1);
            }
            U.p.red[l*25 + o] = b0 + b1;
        }
        __syncthreads();

        // ---- E: both softmaxes + next-step x-build ----
        if (tid < 32) {                       // wave0: s_l softmax
            float tot = 0.f;
#pragma unroll
            for (int o2 = 0; o2 < 24; o2++) tot += U.p.red[tid*25 + o2];
            const float sv = 24.f*cbuf[0] - 2.f*tot;
            float m = sv;
#pragma unroll
            for (int mk = 16; mk >= 1; mk >>= 1) m = fmaxf(m, __shfl_xor(m, mk));
            const float e = __expf(sv - m);
            float ss = e;
#pragma unroll
            for (int mk = 16; mk >= 1; mk >>= 1) ss += __shfl_xor(ss, mk);
            const float r = e * rcp_(ss);
            out[OFF_LAS + t*2048 + b*32 + tid] = r;
            if (t < T_ - 1) U.p.xv[tid] = r * liN;
        } else if (tid >= 64 && tid < 128) {  // wave1: s_g softmax, 4 s/lane
            const int lane = tid - 64;
            float vv0, vv1, vv2, vv3;
            {
                const float t0 = U.p.sgred[lane]     + U.p.sgred[256+lane]     + U.p.sgred[512+lane]     + U.p.sgred[768+lane];
                const float t1 = U.p.sgred[lane+64]  + U.p.sgred[256+lane+64]  + U.p.sgred[512+lane+64]  + U.p.sgred[768+lane+64];
                const float t2 = U.p.sgred[lane+128] + U.p.sgred[256+lane+128] + U.p.sgred[512+lane+128] + U.p.sgred[768+lane+128];
                const float t3 = U.p.sgred[lane+192] + U.p.sgred[256+lane+192] + U.p.sgred[512+lane+192] + U.p.sgred[768+lane+192];
                vv0 = (1.f-LAMDA_)*(24.f*cbuf[1] - 2.f*t0) + LAMDA_*dstf[lane];
                vv1 = (1.f-LAMDA_)*(24.f*cbuf[1] - 2.f*t1) + LAMDA_*dstf[lane+64];
                vv2 = (1.f-LAMDA_)*(24.f*cbuf[1] - 2.f*t2) + LAMDA_*dstf[lane+128];
                vv3 = (1.f-LAMDA_)*(24.f*cbuf[1] - 2.f*t3) + LAMDA_*dstf[lane+192];
            }
            float m = fmaxf(fmaxf(vv0, vv1), fmaxf(vv2, vv3));
#pragma unroll
            for (int mk = 32; mk >= 1; mk >>= 1) m = fmaxf(m, __shfl_xor(m, mk));
            const float e0 = __expf(vv0 - m), e1 = __expf(vv1 - m);
            const float e2 = __expf(vv2 - m), e3 = __expf(vv3 - m);
            float ss = (e0 + e1) + (e2 + e3);
#pragma unroll
            for (int mk = 32; mk >= 1; mk >>= 1) ss += __shfl_xor(ss, mk);
            const float inv = rcp_(ss);
            const float r0 = e0*inv, r1 = e1*inv, r2 = e2*inv, r3 = e3*inv;
            float* og = out + OFF_GAS + t*16384 + b*256;
            og[lane] = r0; og[lane+64] = r1; og[lane+128] = r2; og[lane+192] = r3;
            if (t < T_ - 1) {
                U.p.xv[32+lane]     = r0 * giN0;
                U.p.xv[32+lane+64]  = r1 * giN1;
                U.p.xv[32+lane+128] = r2 * giN2;
                U.p.xv[32+lane+192] = r3 * giN3;
            }
        }
        __syncthreads();
    }
}

extern "C" void kernel_launch(void* const* d_in, const int* in_sizes, int n_in,
                              void* d_out, int out_size, void* d_ws, size_t ws_size,
                              hipStream_t stream)
{
    const float* li   = (const float*)d_in[0];
    const float* gi   = (const float*)d_in[1];
    const float* ls   = (const float*)d_in[2];
    const float* gs   = (const float*)d_in[3];
    const float* dist = (const float*)d_in[4];
    const float* la0  = (const float*)d_in[5];
    const float* ga0  = (const float*)d_in[6];
    const float* Wcl  = (const float*)d_in[7];
    const float* bcl  = (const float*)d_in[8];
    const float* Wll  = (const float*)d_in[9];
    const float* bll  = (const float*)d_in[10];
    const float* vl   = (const float*)d_in[11];
    const float* Wcg  = (const float*)d_in[12];
    const float* bcg  = (const float*)d_in[13];
    const float* Wlg  = (const float*)d_in[14];
    const float* blg  = (const float*)d_in[15];
    const float* vg   = (const float*)d_in[16];
    const float* Wih  = (const float*)d_in[17];
    const float* bih  = (const float*)d_in[18];
    const float* bhh  = (const float*)d_in[19];

    spat_kernel<<<64, 1024, 0, stream>>>(li, gi, ls, gs, dist, la0, ga0,
                                         Wcl, bcl, Wll, bll, vl,
                                         Wcg, bcg, Wlg, blg, vg,
                                         Wih, bih, bhh, (float*)d_out);
}